// Round 1
// baseline (1170.005 us; speedup 1.0000x reference)
//
#include <hip/hip_runtime.h>
#include <math.h>

#define B_    4
#define C_    64
#define N_    4096
#define K_    20
#define OUT_  64
#define EPS_  1e-5f
#define NSL_  0.2f

// ---------------- transpose: xt[b][n][c] = pts[b][c][n] ----------------
__global__ void transpose_kernel(const float* __restrict__ pts, float* __restrict__ xt) {
    __shared__ float tl[64 * 65];
    int b  = blockIdx.x >> 6;          // 64 blocks per batch
    int n0 = (blockIdx.x & 63) << 6;   // 64 points per block
    int t  = threadIdx.x;
#pragma unroll
    for (int s = 0; s < 16; ++s) {
        int lin = s * 256 + t;
        int c = lin >> 6, nn = lin & 63;
        tl[c * 65 + nn] = pts[(b * 64 + c) * 4096 + n0 + nn];
    }
    __syncthreads();
#pragma unroll
    for (int s = 0; s < 16; ++s) {
        int lin = s * 256 + t;
        int nn = lin >> 6, c = lin & 63;
        xt[(b * 4096 + n0 + nn) * 64 + c] = tl[c * 65 + nn];
    }
}

// ---------------- sq[b*N+n] = sum_c pts[b][c][n]^2 ----------------
__global__ void sq_kernel(const float* __restrict__ pts, float* __restrict__ sq) {
    int gid = blockIdx.x * 256 + threadIdx.x;   // 16384 total
    int b = gid >> 12, n = gid & 4095;
    float s = 0.f;
#pragma unroll
    for (int c = 0; c < 64; ++c) {
        float v = pts[(b * 64 + c) * 4096 + n];
        s = fmaf(v, v, s);
    }
    sq[gid] = s;
}

// ---------------- top-20 insertion (sorted desc by (val, -idx)) ----------------
__device__ __forceinline__ void topk_insert(float (&tv)[20], int (&ti)[20], float v, int ix) {
    if (v > tv[19] || (v == tv[19] && ix < ti[19])) {
        tv[19] = v; ti[19] = ix;
#pragma unroll
        for (int p = 19; p > 0; --p) {
            bool sw = (tv[p] > tv[p - 1]) || (tv[p] == tv[p - 1] && ti[p] < ti[p - 1]);
            float av = tv[p - 1]; int ai = ti[p - 1];
            float bv = tv[p];     int bi = ti[p];
            tv[p - 1] = sw ? bv : av;  ti[p - 1] = sw ? bi : ai;
            tv[p]     = sw ? av : bv;  ti[p]     = sw ? ai : bi;
        }
    }
}

// ---------------- knn: 32 queries per block, top-20 indices ----------------
// smem carve (floats): xq[64][32]=2048 | xj[64][128]=8192 | dist[32][132]=4224
// overlay after main loop: candv[5120] at 0, candi[5120] at 5120
__global__ void knn_kernel(const float* __restrict__ pts, const float* __restrict__ sq,
                           int* __restrict__ idxo) {
    __shared__ float smem[14464];
    float* xq   = smem;
    float* xj   = smem + 2048;
    float* dist = smem + 10240;
    float* candv = smem;
    int*   candi = (int*)(smem + 5120);

    int t  = threadIdx.x;
    int b  = blockIdx.x >> 7;            // 128 blocks per batch
    int q0 = (blockIdx.x & 127) << 5;    // 32 queries
    const float* pb = pts + b * 64 * 4096;

    // stage xq[c][32]
#pragma unroll
    for (int s = 0; s < 8; ++s) {
        int lin = s * 256 + t;
        int c = lin >> 5, qq = lin & 31;
        xq[c * 32 + qq] = pb[c * 4096 + q0 + qq];
    }

    int qg = t >> 5;   // 0..7  (4 queries each)
    int jg = t & 31;   // 0..31 (4 j each)
    float sqq[4];
#pragma unroll
    for (int qi = 0; qi < 4; ++qi) sqq[qi] = sq[b * 4096 + q0 + qg * 4 + qi];

    float tv[20]; int ti[20];
#pragma unroll
    for (int p = 0; p < 20; ++p) { tv[p] = -INFINITY; ti[p] = 0x7fffffff; }

    int q_s = t >> 3, slot = t & 7;

    for (int tile = 0; tile < 32; ++tile) {
        int j0 = tile * 128;
        __syncthreads();
        // stage xj[c][128] as float4
#pragma unroll
        for (int s = 0; s < 8; ++s) {
            int lin4 = s * 256 + t;
            int c = lin4 >> 5, jj4 = lin4 & 31;
            float4 v = *(const float4*)&pb[c * 4096 + j0 + jj4 * 4];
            *(float4*)&xj[c * 128 + jj4 * 4] = v;
        }
        __syncthreads();

        float acc[4][4] = {};
#pragma unroll 4
        for (int c = 0; c < 64; ++c) {
            const float4 a4 = *(const float4*)&xq[c * 32 + qg * 4];
            const float4 b4 = *(const float4*)&xj[c * 128 + jg * 4];
            const float aa[4] = {a4.x, a4.y, a4.z, a4.w};
            const float bb[4] = {b4.x, b4.y, b4.z, b4.w};
#pragma unroll
            for (int qi = 0; qi < 4; ++qi)
#pragma unroll
                for (int ji = 0; ji < 4; ++ji)
                    acc[qi][ji] = fmaf(aa[qi], bb[ji], acc[qi][ji]);
        }

        const float4 sj4 = *(const float4*)&sq[b * 4096 + j0 + jg * 4];
        const float sjv[4] = {sj4.x, sj4.y, sj4.z, sj4.w};
#pragma unroll
        for (int qi = 0; qi < 4; ++qi) {
            float4 nd;
            nd.x = 2.0f * acc[qi][0] - sqq[qi] - sjv[0];
            nd.y = 2.0f * acc[qi][1] - sqq[qi] - sjv[1];
            nd.z = 2.0f * acc[qi][2] - sqq[qi] - sjv[2];
            nd.w = 2.0f * acc[qi][3] - sqq[qi] - sjv[3];
            *(float4*)&dist[(qg * 4 + qi) * 132 + jg * 4] = nd;
        }
        __syncthreads();

        // per-thread scan: query q_s, j = i*8 + slot
#pragma unroll 1
        for (int i = 0; i < 16; ++i) {
            int jl = i * 8 + slot;
            float v = dist[q_s * 132 + jl];
            topk_insert(tv, ti, v, j0 + jl);
        }
    }

    __syncthreads();
#pragma unroll
    for (int p = 0; p < 20; ++p) { candv[t * 20 + p] = tv[p]; candi[t * 20 + p] = ti[p]; }
    __syncthreads();

    if (t < 32) {
        float mv[20]; int mi[20];
#pragma unroll
        for (int p = 0; p < 20; ++p) { mv[p] = -INFINITY; mi[p] = 0x7fffffff; }
#pragma unroll 1
        for (int s = 0; s < 8; ++s) {
#pragma unroll 1
            for (int p = 0; p < 20; ++p) {
                float v = candv[(t * 8 + s) * 20 + p];
                int  ix = candi[(t * 8 + s) * 20 + p];
                topk_insert(mv, mi, v, ix);
            }
        }
#pragma unroll
        for (int p = 0; p < 20; ++p)
            idxo[(b * 4096 + q0 + t) * 20 + p] = mi[p];
    }
}

// ---------------- conv: y = W1*fj + W2'*fi ; stats + max_k ----------------
// 2 points per block. W1l/W2l stride 68 (16B-aligned rows, 8-way worst case).
__global__ void conv_kernel(const float* __restrict__ xt, const float* __restrict__ W,
                            const int* __restrict__ idxi, float* __restrict__ ymax,
                            float* __restrict__ stats) {
    __shared__ float W1l[64 * 68];
    __shared__ float W2l[64 * 68];
    __shared__ float fjs[21 * 64];
    __shared__ int   jid[24];
    __shared__ float red[3 * 4 * 64];

    int t   = threadIdx.x;
    int bn0 = blockIdx.x * 2;
    int b   = bn0 >> 12;
    int o   = t & 63, kg = t >> 6;

    // stage W (W2' = W[:,64:] - W[:,:64])
#pragma unroll
    for (int s = 0; s < 16; ++s) {
        int lin = s * 256 + t;
        int oo = lin >> 6, c = lin & 63;
        float w1 = W[oo * 128 + c];
        float w2 = W[oo * 128 + 64 + c] - w1;
        W1l[oo * 68 + c] = w1;
        W2l[oo * 68 + c] = w2;
    }

    for (int nn = 0; nn < 2; ++nn) {
        int bn = bn0 + nn;
        int n  = bn & 4095;
        __syncthreads();
        if (t < 21) jid[t] = (t < 20) ? idxi[bn * 20 + t] : n;
        __syncthreads();
#pragma unroll
        for (int s = 0; s < 6; ++s) {
            int lin = s * 256 + t;
            if (lin < 1344) {
                int k = lin >> 6, c = lin & 63;
                fjs[k * 64 + c] = xt[(b * 4096 + jid[k]) * 64 + c];
            }
        }
        __syncthreads();

        float accu[5] = {0.f, 0.f, 0.f, 0.f, 0.f};
        float acct = 0.f;
#pragma unroll
        for (int cc = 0; cc < 4; ++cc) {
            float4 w1r[4], w2r[4];
#pragma unroll
            for (int q = 0; q < 4; ++q) {
                w1r[q] = *(const float4*)&W1l[o * 68 + cc * 16 + q * 4];
                w2r[q] = *(const float4*)&W2l[o * 68 + cc * 16 + q * 4];
            }
#pragma unroll
            for (int q = 0; q < 4; ++q) {
                float4 f = *(const float4*)&fjs[20 * 64 + cc * 16 + q * 4];
                acct = fmaf(f.x, w2r[q].x, acct);
                acct = fmaf(f.y, w2r[q].y, acct);
                acct = fmaf(f.z, w2r[q].z, acct);
                acct = fmaf(f.w, w2r[q].w, acct);
            }
#pragma unroll
            for (int kk = 0; kk < 5; ++kk) {
                int k = kg * 5 + kk;
#pragma unroll
                for (int q = 0; q < 4; ++q) {
                    float4 f = *(const float4*)&fjs[k * 64 + cc * 16 + q * 4];
                    accu[kk] = fmaf(f.x, w1r[q].x, accu[kk]);
                    accu[kk] = fmaf(f.y, w1r[q].y, accu[kk]);
                    accu[kk] = fmaf(f.z, w1r[q].z, accu[kk]);
                    accu[kk] = fmaf(f.w, w1r[q].w, accu[kk]);
                }
            }
        }

        float ymx = -INFINITY, ls = 0.f, lq = 0.f;
#pragma unroll
        for (int kk = 0; kk < 5; ++kk) {
            float y = accu[kk] + acct;
            ymx = fmaxf(ymx, y);
            ls += y;
            lq  = fmaf(y, y, lq);
        }
        red[0 * 256 + kg * 64 + o] = ymx;
        red[1 * 256 + kg * 64 + o] = ls;
        red[2 * 256 + kg * 64 + o] = lq;
        __syncthreads();
        if (t < 64) {
            float m  = fmaxf(fmaxf(red[t], red[64 + t]), fmaxf(red[128 + t], red[192 + t]));
            float s_ = red[256 + t] + red[256 + 64 + t] + red[256 + 128 + t] + red[256 + 192 + t];
            float q_ = red[512 + t] + red[512 + 64 + t] + red[512 + 128 + t] + red[512 + 192 + t];
            ymax[bn * 64 + t] = m;
            atomicAdd(&stats[b * 64 + t], s_);
            atomicAdd(&stats[256 + b * 64 + t], q_);
        }
    }
}

// ---------------- finalize: out[b][o][n] = leaky((ymax-mean)*rsqrt(var+eps)) ----------------
__global__ void finalize_kernel(const float* __restrict__ ymax, const float* __restrict__ stats,
                                float* __restrict__ out) {
    int gid = blockIdx.x * 256 + threadIdx.x;   // 1,048,576
    int n = gid & 4095;
    int o = (gid >> 12) & 63;
    int b = gid >> 18;
    const float cnt = (float)(N_ * K_);
    float mean = stats[b * 64 + o] / cnt;
    float var  = stats[256 + b * 64 + o] / cnt - mean * mean;
    float inv  = rsqrtf(var + EPS_);
    float v = ymax[(b * 4096 + n) * 64 + o];
    float z = (v - mean) * inv;
    out[gid] = z >= 0.f ? z : NSL_ * z;
}

extern "C" void kernel_launch(void* const* d_in, const int* in_sizes, int n_in,
                              void* d_out, int out_size, void* d_ws, size_t ws_size,
                              hipStream_t stream) {
    const float* pts = (const float*)d_in[0];
    const float* W   = (const float*)d_in[1];
    float* out = (float*)d_out;
    char* ws = (char*)d_ws;

    float* xt    = (float*)(ws);                 // 4,194,304 B
    float* sq    = (float*)(ws + 4194304);       //    65,536 B
    int*   idx   = (int*)  (ws + 4259840);       // 1,310,720 B
    float* ymax  = (float*)(ws + 5570560);       // 4,194,304 B
    float* stats = (float*)(ws + 9764864);       //     2,048 B

    hipMemsetAsync(stats, 0, 512 * sizeof(float), stream);
    transpose_kernel<<<256, 256, 0, stream>>>(pts, xt);
    sq_kernel<<<64, 256, 0, stream>>>(pts, sq);
    knn_kernel<<<512, 256, 0, stream>>>(pts, sq, idx);
    conv_kernel<<<8192, 256, 0, stream>>>(xt, W, idx, ymax, stats);
    finalize_kernel<<<4096, 256, 0, stream>>>(ymax, stats, out);
}

// Round 2
// 475.302 us; speedup vs baseline: 2.4616x; 2.4616x over previous
//
#include <hip/hip_runtime.h>
#include <math.h>

#define B_    4
#define C_    64
#define N_    4096
#define K_    20
#define OUT_  64
#define EPS_  1e-5f
#define NSL_  0.2f
#define QCAP  64

// ---------------- sq[b*N+n] = sum_c pts[b][c][n]^2 ----------------
__global__ void sq_kernel(const float* __restrict__ pts, float* __restrict__ sq) {
    int gid = blockIdx.x * 256 + threadIdx.x;   // 16384 total
    int b = gid >> 12, n = gid & 4095;
    float s = 0.f;
#pragma unroll
    for (int c = 0; c < 64; ++c) {
        float v = pts[(b * 64 + c) * 4096 + n];
        s = fmaf(v, v, s);
    }
    sq[gid] = s;
}

// ---------------- top-20 insertion (sorted desc by (val, -idx)) ----------------
__device__ __forceinline__ void topk_insert(float (&tv)[20], int (&ti)[20], float v, int ix) {
    if (v > tv[19] || (v == tv[19] && ix < ti[19])) {
        tv[19] = v; ti[19] = ix;
#pragma unroll
        for (int p = 19; p > 0; --p) {
            bool sw = (tv[p] > tv[p - 1]) || (tv[p] == tv[p - 1] && ti[p] < ti[p - 1]);
            float av = tv[p - 1]; int ai = ti[p - 1];
            float bv = tv[p];     int bi = ti[p];
            tv[p - 1] = sw ? bv : av;  ti[p - 1] = sw ? bi : ai;
            tv[p]     = sw ? av : bv;  ti[p]     = sw ? ai : bi;
        }
    }
}

// ---------------- knn v2: sample-threshold top-20 ----------------
// 32 queries/block, 512 blocks. Pass A: distances + branchless per-thread
// top-2 per query -> safe threshold tau (20th of 64 subset values <= true
// 20th). Pass B: recompute (identical FMA order) + filter v >= tau into
// per-query LDS queue. Final: exact (v desc, idx asc) top-20 of ~30 entries.
__global__ void knn2_kernel(const float* __restrict__ pts, const float* __restrict__ sq,
                            int* __restrict__ idxo) {
    __shared__ float xq[2048];          // [c][32]
    __shared__ float xj[8192];          // [c][128]  (overlaid: sarr[32][64])
    __shared__ float qv[32 * QCAP];
    __shared__ int   qix[32 * QCAP];
    __shared__ float tau[32];
    __shared__ int   qcnt[32];

    int t  = threadIdx.x;
    int b  = blockIdx.x >> 7;
    int q0 = (blockIdx.x & 127) << 5;
    const float* pb = pts + b * 64 * 4096;

#pragma unroll
    for (int s = 0; s < 8; ++s) {
        int lin = s * 256 + t;
        int c = lin >> 5, qq = lin & 31;
        xq[c * 32 + qq] = pb[c * 4096 + q0 + qq];
    }

    int qg = t >> 5;   // 0..7  (4 queries each)
    int jg = t & 31;   // 0..31 (4 j each)
    float sqq[4];
#pragma unroll
    for (int qi = 0; qi < 4; ++qi) sqq[qi] = sq[b * 4096 + q0 + qg * 4 + qi];

    float t0[4], t1[4];
#pragma unroll
    for (int qi = 0; qi < 4; ++qi) { t0[qi] = -INFINITY; t1[qi] = -INFINITY; }

    // ---------------- PASS A ----------------
    for (int tile = 0; tile < 32; ++tile) {
        int j0 = tile * 128;
        __syncthreads();
#pragma unroll
        for (int s = 0; s < 8; ++s) {
            int lin4 = s * 256 + t;
            int c = lin4 >> 5, jj4 = lin4 & 31;
            float4 v = *(const float4*)&pb[c * 4096 + j0 + jj4 * 4];
            *(float4*)&xj[c * 128 + jj4 * 4] = v;
        }
        __syncthreads();

        float acc[4][4] = {};
#pragma unroll 4
        for (int c = 0; c < 64; ++c) {
            const float4 a4 = *(const float4*)&xq[c * 32 + qg * 4];
            const float4 b4 = *(const float4*)&xj[c * 128 + jg * 4];
            const float aa[4] = {a4.x, a4.y, a4.z, a4.w};
            const float bb[4] = {b4.x, b4.y, b4.z, b4.w};
#pragma unroll
            for (int qi = 0; qi < 4; ++qi)
#pragma unroll
                for (int ji = 0; ji < 4; ++ji)
                    acc[qi][ji] = fmaf(aa[qi], bb[ji], acc[qi][ji]);
        }

        const float4 sj4 = *(const float4*)&sq[b * 4096 + j0 + jg * 4];
        const float sjv[4] = {sj4.x, sj4.y, sj4.z, sj4.w};
#pragma unroll
        for (int qi = 0; qi < 4; ++qi) {
#pragma unroll
            for (int ji = 0; ji < 4; ++ji) {
                float v = 2.0f * acc[qi][ji] - sqq[qi] - sjv[ji];
                t1[qi] = fminf(t0[qi], fmaxf(t1[qi], v));   // branchless top-2
                t0[qi] = fmaxf(t0[qi], v);
            }
        }
    }

    __syncthreads();
    // dump per-thread top-2 into sarr (overlaid on xj)
    float* sarr = xj;
#pragma unroll
    for (int qi = 0; qi < 4; ++qi) {
        int q = qg * 4 + qi;
        sarr[q * 64 + jg * 2 + 0] = t0[qi];
        sarr[q * 64 + jg * 2 + 1] = t1[qi];
    }
    __syncthreads();

    if (t < 32) {
        float tv[20];
#pragma unroll
        for (int p = 0; p < 20; ++p) tv[p] = -INFINITY;
#pragma unroll 1
        for (int s = 0; s < 64; ++s) {
            float v = sarr[t * 64 + s];
            if (v > tv[19]) {
                tv[19] = v;
#pragma unroll
                for (int p = 19; p > 0; --p) {
                    float a = tv[p - 1], bb2 = tv[p];
                    tv[p - 1] = fmaxf(a, bb2);
                    tv[p]     = fminf(a, bb2);
                }
            }
        }
        tau[t] = tv[19];
        qcnt[t] = 0;
    }
    __syncthreads();

    float taur[4];
#pragma unroll
    for (int qi = 0; qi < 4; ++qi) taur[qi] = tau[qg * 4 + qi];

    // ---------------- PASS B ----------------
    for (int tile = 0; tile < 32; ++tile) {
        int j0 = tile * 128;
        __syncthreads();
#pragma unroll
        for (int s = 0; s < 8; ++s) {
            int lin4 = s * 256 + t;
            int c = lin4 >> 5, jj4 = lin4 & 31;
            float4 v = *(const float4*)&pb[c * 4096 + j0 + jj4 * 4];
            *(float4*)&xj[c * 128 + jj4 * 4] = v;
        }
        __syncthreads();

        float acc[4][4] = {};
#pragma unroll 4
        for (int c = 0; c < 64; ++c) {
            const float4 a4 = *(const float4*)&xq[c * 32 + qg * 4];
            const float4 b4 = *(const float4*)&xj[c * 128 + jg * 4];
            const float aa[4] = {a4.x, a4.y, a4.z, a4.w};
            const float bb[4] = {b4.x, b4.y, b4.z, b4.w};
#pragma unroll
            for (int qi = 0; qi < 4; ++qi)
#pragma unroll
                for (int ji = 0; ji < 4; ++ji)
                    acc[qi][ji] = fmaf(aa[qi], bb[ji], acc[qi][ji]);
        }

        const float4 sj4 = *(const float4*)&sq[b * 4096 + j0 + jg * 4];
        const float sjv[4] = {sj4.x, sj4.y, sj4.z, sj4.w};
#pragma unroll
        for (int qi = 0; qi < 4; ++qi) {
#pragma unroll
            for (int ji = 0; ji < 4; ++ji) {
                float v = 2.0f * acc[qi][ji] - sqq[qi] - sjv[ji];
                if (v >= taur[qi]) {
                    int q = qg * 4 + qi;
                    int p = atomicAdd(&qcnt[q], 1);
                    if (p < QCAP) { qv[q * QCAP + p] = v; qix[q * QCAP + p] = j0 + jg * 4 + ji; }
                }
            }
        }
    }

    __syncthreads();
    if (t < 32) {
        int cnt = qcnt[t]; if (cnt > QCAP) cnt = QCAP;
        float tv[20]; int ti[20];
#pragma unroll
        for (int p = 0; p < 20; ++p) { tv[p] = -INFINITY; ti[p] = 0x7fffffff; }
#pragma unroll 1
        for (int s = 0; s < cnt; ++s)
            topk_insert(tv, ti, qv[t * QCAP + s], qix[t * QCAP + s]);
#pragma unroll
        for (int p = 0; p < 20; ++p)
            idxo[(b * 4096 + q0 + t) * 20 + p] = ti[p];
    }
}

// ---------------- ugemm: u1 = pts^T @ W1^T, u2 = pts^T @ (W2-W1)^T ----------------
// block: 64 o-lanes x 4 j-groups, each thread 16 j. 256 blocks.
__global__ void ugemm_kernel(const float* __restrict__ pts, const float* __restrict__ W,
                             float* __restrict__ u1, float* __restrict__ u2) {
    __shared__ float W1l[64 * 65];
    __shared__ float W2l[64 * 65];
    int t  = threadIdx.x;
    int b  = blockIdx.x >> 6;
    int j0 = (blockIdx.x & 63) << 6;
    int o  = t & 63, jg = t >> 6;

#pragma unroll
    for (int s = 0; s < 16; ++s) {
        int lin = s * 256 + t;
        int oo = lin >> 6, c = lin & 63;
        float w1 = W[oo * 128 + c];
        W1l[oo * 65 + c] = w1;
        W2l[oo * 65 + c] = W[oo * 128 + 64 + c] - w1;
    }
    __syncthreads();

    float acc1[16], acc2[16];
#pragma unroll
    for (int jj = 0; jj < 16; ++jj) { acc1[jj] = 0.f; acc2[jj] = 0.f; }

    const float* pbj = pts + b * 64 * 4096 + j0 + jg * 16;
#pragma unroll 4
    for (int c = 0; c < 64; ++c) {
        float w1 = W1l[o * 65 + c];
        float w2 = W2l[o * 65 + c];
#pragma unroll
        for (int jj = 0; jj < 16; ++jj) {
            float p = pbj[c * 4096 + jj];      // wave-uniform -> scalar loads
            acc1[jj] = fmaf(w1, p, acc1[jj]);
            acc2[jj] = fmaf(w2, p, acc2[jj]);
        }
    }
#pragma unroll
    for (int jj = 0; jj < 16; ++jj) {
        int j = j0 + jg * 16 + jj;
        u1[(b * 4096 + j) * 64 + o] = acc1[jj];
        u2[(b * 4096 + j) * 64 + o] = acc2[jj];
    }
}

// ---------------- gather: y[n,k,o] = u1[idx[n,k],o] + u2[n,o]; max_k + stats ----------------
__global__ void gather_kernel(const float* __restrict__ u1, const float* __restrict__ u2,
                              const int* __restrict__ idxi, float* __restrict__ ymax,
                              float* __restrict__ stats) {
    __shared__ float red[2 * 4 * 64];
    int t  = threadIdx.x;
    int o  = t & 63, ng = t >> 6;
    int b  = blockIdx.x >> 10;                 // 1024 blocks per batch
    int n  = ((blockIdx.x & 1023) << 2) + ng;
    int bn = b * 4096 + n;

    float v2 = u2[bn * 64 + o];
    float m = -INFINITY, s = 0.f, q = 0.f;
#pragma unroll
    for (int k = 0; k < 20; ++k) {
        int j = idxi[bn * 20 + k];             // wave-uniform -> scalar
        float y = u1[(b * 4096 + j) * 64 + o] + v2;
        m = fmaxf(m, y);
        s += y;
        q = fmaf(y, y, q);
    }
    ymax[bn * 64 + o] = m;
    red[ng * 64 + o] = s;
    red[256 + ng * 64 + o] = q;
    __syncthreads();
    if (t < 64) {
        float s_ = red[t] + red[64 + t] + red[128 + t] + red[192 + t];
        float q_ = red[256 + t] + red[256 + 64 + t] + red[256 + 128 + t] + red[256 + 192 + t];
        atomicAdd(&stats[b * 64 + t], s_);
        atomicAdd(&stats[256 + b * 64 + t], q_);
    }
}

// ---------------- finalize ----------------
__global__ void finalize_kernel(const float* __restrict__ ymax, const float* __restrict__ stats,
                                float* __restrict__ out) {
    int gid = blockIdx.x * 256 + threadIdx.x;   // 1,048,576
    int n = gid & 4095;
    int o = (gid >> 12) & 63;
    int b = gid >> 18;
    const float cnt = (float)(N_ * K_);
    float mean = stats[b * 64 + o] / cnt;
    float var  = stats[256 + b * 64 + o] / cnt - mean * mean;
    float inv  = rsqrtf(var + EPS_);
    float v = ymax[(b * 4096 + n) * 64 + o];
    float z = (v - mean) * inv;
    out[gid] = z >= 0.f ? z : NSL_ * z;
}

extern "C" void kernel_launch(void* const* d_in, const int* in_sizes, int n_in,
                              void* d_out, int out_size, void* d_ws, size_t ws_size,
                              hipStream_t stream) {
    const float* pts = (const float*)d_in[0];
    const float* W   = (const float*)d_in[1];
    float* out = (float*)d_out;
    char* ws = (char*)d_ws;

    float* sq    = (float*)(ws);                  //    65,536 B
    int*   idx   = (int*)  (ws + 65536);          // 1,310,720 B
    float* u1    = (float*)(ws + 1376256);        // 4,194,304 B
    float* u2    = (float*)(ws + 5570560);        // 4,194,304 B
    float* ymax  = (float*)(ws + 9764864);        // 4,194,304 B
    float* stats = (float*)(ws + 13959168);       //     2,048 B

    hipMemsetAsync(stats, 0, 512 * sizeof(float), stream);
    sq_kernel<<<64, 256, 0, stream>>>(pts, sq);
    knn2_kernel<<<512, 256, 0, stream>>>(pts, sq, idx);
    ugemm_kernel<<<256, 256, 0, stream>>>(pts, W, u1, u2);
    gather_kernel<<<4096, 256, 0, stream>>>(u1, u2, idx, ymax, stats);
    finalize_kernel<<<4096, 256, 0, stream>>>(ymax, stats, out);
}

// Round 6
// 346.655 us; speedup vs baseline: 3.3751x; 1.3711x over previous
//
#include <hip/hip_runtime.h>
#include <math.h>

#define B_    4
#define C_    64
#define N_    4096
#define K_    20
#define OUT_  64
#define EPS_  1e-5f
#define NSL_  0.2f
#define MARGIN_ 0.05f

typedef _Float16 h4 __attribute__((ext_vector_type(4)));
typedef float    f4 __attribute__((ext_vector_type(4)));

// ---------------- split: Xh/Xl[(b*16+g)*4096+n][i] = f16split(pts[b][g*4+i][n]) ----------------
__global__ void split_kernel(const float* __restrict__ pts,
                             h4* __restrict__ Xh, h4* __restrict__ Xl) {
    int gid = blockIdx.x * 256 + threadIdx.x;      // 262144 = 4*16*4096
    int n = gid & 4095;
    int g = (gid >> 12) & 15;
    int b = gid >> 16;
    const float* p = pts + (size_t)(b * 64 + g * 4) * 4096 + n;
    h4 hh, ll;
#pragma unroll
    for (int i = 0; i < 4; ++i) {
        float x = p[(size_t)i * 4096];
        _Float16 h = (_Float16)x;
        hh[i] = h;
        ll[i] = (_Float16)(x - (float)h);
    }
    Xh[gid] = hh;
    Xl[gid] = ll;
}

// ---------------- transpose: xt[b][n][c] = pts[b][c][n] ----------------
__global__ void transpose_kernel(const float* __restrict__ pts, float* __restrict__ xt) {
    __shared__ float tl[64 * 65];
    int b  = blockIdx.x >> 6;
    int n0 = (blockIdx.x & 63) << 6;
    int t  = threadIdx.x;
#pragma unroll
    for (int s = 0; s < 16; ++s) {
        int lin = s * 256 + t;
        int c = lin >> 6, nn = lin & 63;
        tl[c * 65 + nn] = pts[(size_t)(b * 64 + c) * 4096 + n0 + nn];
    }
    __syncthreads();
#pragma unroll
    for (int s = 0; s < 16; ++s) {
        int lin = s * 256 + t;
        int nn = lin >> 6, c = lin & 63;
        xt[(size_t)(b * 4096 + n0 + nn) * 64 + c] = tl[c * 65 + nn];
    }
}

// ---------------- sq[b*N+n] = sum_c pts[b][c][n]^2 ----------------
__global__ void sq_kernel(const float* __restrict__ pts, float* __restrict__ sq) {
    int gid = blockIdx.x * 256 + threadIdx.x;   // 16384
    int b = gid >> 12, n = gid & 4095;
    float s = 0.f;
#pragma unroll
    for (int c = 0; c < 64; ++c) {
        float v = pts[(size_t)(b * 64 + c) * 4096 + n];
        s = fmaf(v, v, s);
    }
    sq[gid] = s;
}

// ---------------- top-20 insertion (sorted desc by (val, -idx)) ----------------
__device__ __forceinline__ void topk_insert(float (&tv)[20], int (&ti)[20], float v, int ix) {
    if (v > tv[19] || (v == tv[19] && ix < ti[19])) {
        tv[19] = v; ti[19] = ix;
#pragma unroll
        for (int p = 19; p > 0; --p) {
            bool sw = (tv[p] > tv[p - 1]) || (tv[p] == tv[p - 1] && ti[p] < ti[p - 1]);
            float av = tv[p - 1]; int ai = ti[p - 1];
            float bv = tv[p];     int bi = ti[p];
            tv[p - 1] = sw ? bv : av;  ti[p - 1] = sw ? bi : ai;
            tv[p]     = sw ? av : bv;  ti[p]     = sw ? ai : bi;
        }
    }
}

// ---------------- MFMA distance tile: acc[qs][js] += split-f16 G ----------------
__device__ __forceinline__ void mfma_tile(const h4* jHs, const h4* jLs,
                                          const h4* qHs, const h4* qLs,
                                          int arow, int kgrp, int jl0, int jl1,
                                          f4 (&acc)[2][2]) {
#pragma unroll
    for (int kc = 0; kc < 4; ++kc) {
        int g = kc * 4 + kgrp;
        h4 Ah0 = qHs[g * 32 + arow];
        h4 Ah1 = qHs[g * 32 + 16 + arow];
        h4 Al0 = qLs[g * 32 + arow];
        h4 Al1 = qLs[g * 32 + 16 + arow];
        h4 Bh0 = jHs[g * 128 + jl0];
        h4 Bh1 = jHs[g * 128 + jl1];
        h4 Bl0 = jLs[g * 128 + jl0];
        h4 Bl1 = jLs[g * 128 + jl1];
        acc[0][0] = __builtin_amdgcn_mfma_f32_16x16x16f16(Ah0, Bh0, acc[0][0], 0, 0, 0);
        acc[0][0] = __builtin_amdgcn_mfma_f32_16x16x16f16(Ah0, Bl0, acc[0][0], 0, 0, 0);
        acc[0][0] = __builtin_amdgcn_mfma_f32_16x16x16f16(Al0, Bh0, acc[0][0], 0, 0, 0);
        acc[0][1] = __builtin_amdgcn_mfma_f32_16x16x16f16(Ah0, Bh1, acc[0][1], 0, 0, 0);
        acc[0][1] = __builtin_amdgcn_mfma_f32_16x16x16f16(Ah0, Bl1, acc[0][1], 0, 0, 0);
        acc[0][1] = __builtin_amdgcn_mfma_f32_16x16x16f16(Al0, Bh1, acc[0][1], 0, 0, 0);
        acc[1][0] = __builtin_amdgcn_mfma_f32_16x16x16f16(Ah1, Bh0, acc[1][0], 0, 0, 0);
        acc[1][0] = __builtin_amdgcn_mfma_f32_16x16x16f16(Ah1, Bl0, acc[1][0], 0, 0, 0);
        acc[1][0] = __builtin_amdgcn_mfma_f32_16x16x16f16(Al1, Bh0, acc[1][0], 0, 0, 0);
        acc[1][1] = __builtin_amdgcn_mfma_f32_16x16x16f16(Ah1, Bh1, acc[1][1], 0, 0, 0);
        acc[1][1] = __builtin_amdgcn_mfma_f32_16x16x16f16(Ah1, Bl1, acc[1][1], 0, 0, 0);
        acc[1][1] = __builtin_amdgcn_mfma_f32_16x16x16f16(Al1, Bh1, acc[1][1], 0, 0, 0);
    }
}

// ---------------- knn3: MFMA pass A (threshold) + pass B (filter) + exact re-rank ----------------
// LDS map (bytes):
//   jHs  [16][128] h4      0 .. 16384
//   jLs  [16][128] h4  16384 .. 32768
//   qHs  [16][32]  h4  32768 .. 36864
//   qLs  [16][32]  h4  36864 .. 40960
//   xqe  [32][68]  f32 40960 .. 49664
//   sqj  [128]     f32 49664 .. 50176
//   tauv [32]      f32 50176 .. 50304
//   qcnt [32]      int 50304 .. 50432
//   qix  [64][33]  int 50432 .. 58880
//   coll [128][33] f32 overlay @0 (after pass A)
//   qval [64][33]  f32 overlay @0 (after pass B)
__global__ __launch_bounds__(256) void knn3_kernel(
        const h4* __restrict__ Xh, const h4* __restrict__ Xl,
        const float* __restrict__ xt, const float* __restrict__ sqa,
        int* __restrict__ idxo) {
    __shared__ __align__(16) char smem[58880];
    h4*    jHs  = (h4*)(smem);
    h4*    jLs  = (h4*)(smem + 16384);
    h4*    qHs  = (h4*)(smem + 32768);
    h4*    qLs  = (h4*)(smem + 36864);
    float* xqe  = (float*)(smem + 40960);
    float* sqj  = (float*)(smem + 49664);
    float* tauv = (float*)(smem + 50176);
    int*   qcnt = (int*)  (smem + 50304);
    int*   qix  = (int*)  (smem + 50432);
    float* coll = (float*)(smem);
    float* qval = (float*)(smem);

    int t    = threadIdx.x;
    int lane = t & 63, w = t >> 6;
    int b    = blockIdx.x >> 7;
    int q0   = (blockIdx.x & 127) << 5;
    int bb16 = b * 16;
    const float* sqg = sqa + b * 4096;

    // stage query fragments + exact query rows
#pragma unroll
    for (int s = 0; s < 2; ++s) {
        int lin = s * 256 + t;
        int g = lin >> 5, q = lin & 31;
        qHs[lin] = Xh[(size_t)(bb16 + g) * 4096 + q0 + q];
        qLs[lin] = Xl[(size_t)(bb16 + g) * 4096 + q0 + q];
    }
#pragma unroll
    for (int s = 0; s < 8; ++s) {
        int lin = s * 256 + t;
        int q = lin >> 6, c = lin & 63;
        xqe[q * 68 + c] = xt[((size_t)(b * 4096 + q0 + q)) * 64 + c];
    }

    int arow = lane & 15;      // A-row / B-col / D-col
    int kgrp = lane >> 4;      // k-group; D-row base = 4*kgrp
    int jl0  = w * 32 + arow;  // wave w owns j-subtiles 2w, 2w+1
    int jl1  = jl0 + 16;

    float sqr[2][4];
#pragma unroll
    for (int qs = 0; qs < 2; ++qs)
#pragma unroll
        for (int r = 0; r < 4; ++r)
            sqr[qs][r] = sqg[q0 + qs * 16 + 4 * kgrp + r];

    float t0v[2][4], t1v[2][4];
#pragma unroll
    for (int qs = 0; qs < 2; ++qs)
#pragma unroll
        for (int r = 0; r < 4; ++r) { t0v[qs][r] = -INFINITY; t1v[qs][r] = -INFINITY; }

    // ---------------- PASS A: approx distances, per-lane top-2 ----------------
    for (int step = 0; step < 32; ++step) {
        __syncthreads();
#pragma unroll
        for (int s = 0; s < 8; ++s) {
            int lin = s * 256 + t;
            int g = lin >> 7, jj = lin & 127;
            jHs[lin] = Xh[(size_t)(bb16 + g) * 4096 + step * 128 + jj];
            jLs[lin] = Xl[(size_t)(bb16 + g) * 4096 + step * 128 + jj];
        }
        if (t < 128) sqj[t] = sqg[step * 128 + t];
        __syncthreads();

        f4 acc[2][2];
#pragma unroll
        for (int qs = 0; qs < 2; ++qs)
#pragma unroll
            for (int js = 0; js < 2; ++js) acc[qs][js] = (f4){0.f, 0.f, 0.f, 0.f};
        mfma_tile(jHs, jLs, qHs, qLs, arow, kgrp, jl0, jl1, acc);

        float sj0 = sqj[jl0], sj1 = sqj[jl1];
#pragma unroll
        for (int qs = 0; qs < 2; ++qs)
#pragma unroll
            for (int r = 0; r < 4; ++r) {
                float v0 = 2.f * acc[qs][0][r] - sqr[qs][r] - sj0;
                float v1 = 2.f * acc[qs][1][r] - sqr[qs][r] - sj1;
                t1v[qs][r] = fminf(t0v[qs][r], fmaxf(t1v[qs][r], v0));
                t0v[qs][r] = fmaxf(t0v[qs][r], v0);
                t1v[qs][r] = fminf(t0v[qs][r], fmaxf(t1v[qs][r], v1));
                t0v[qs][r] = fmaxf(t0v[qs][r], v1);
            }
    }

    // dump top-2 candidates (values only), stride-33 to avoid bank conflicts
    __syncthreads();
#pragma unroll
    for (int qs = 0; qs < 2; ++qs)
#pragma unroll
        for (int r = 0; r < 4; ++r) {
            int q  = qs * 16 + 4 * kgrp + r;
            int s0 = w * 32 + arow * 2;
            coll[(s0 + 0) * 33 + q] = t0v[qs][r];
            coll[(s0 + 1) * 33 + q] = t1v[qs][r];
        }
    __syncthreads();

    if (t < 32) {
        float tv[20];
#pragma unroll
        for (int p = 0; p < 20; ++p) tv[p] = -INFINITY;
#pragma unroll 1
        for (int s = 0; s < 128; ++s) {
            float v = coll[s * 33 + t];
            if (v > tv[19]) {
                tv[19] = v;
#pragma unroll
                for (int p = 19; p > 0; --p) {
                    float a = tv[p - 1], bb = tv[p];
                    tv[p - 1] = fmaxf(a, bb);
                    tv[p]     = fminf(a, bb);
                }
            }
        }
        tauv[t] = tv[19] - MARGIN_;   // safe: tau <= e20 + delta, margin >= 2*delta
        qcnt[t] = 0;
    }
    __syncthreads();

    float taum[2][4];
#pragma unroll
    for (int qs = 0; qs < 2; ++qs)
#pragma unroll
        for (int r = 0; r < 4; ++r)
            taum[qs][r] = tauv[qs * 16 + 4 * kgrp + r];

    // ---------------- PASS B: re-sweep, filter into per-query index queues ----------------
    for (int step = 0; step < 32; ++step) {
        __syncthreads();
#pragma unroll
        for (int s = 0; s < 8; ++s) {
            int lin = s * 256 + t;
            int g = lin >> 7, jj = lin & 127;
            jHs[lin] = Xh[(size_t)(bb16 + g) * 4096 + step * 128 + jj];
            jLs[lin] = Xl[(size_t)(bb16 + g) * 4096 + step * 128 + jj];
        }
        if (t < 128) sqj[t] = sqg[step * 128 + t];
        __syncthreads();

        f4 acc[2][2];
#pragma unroll
        for (int qs = 0; qs < 2; ++qs)
#pragma unroll
            for (int js = 0; js < 2; ++js) acc[qs][js] = (f4){0.f, 0.f, 0.f, 0.f};
        mfma_tile(jHs, jLs, qHs, qLs, arow, kgrp, jl0, jl1, acc);

        float sj0 = sqj[jl0], sj1 = sqj[jl1];
#pragma unroll
        for (int qs = 0; qs < 2; ++qs)
#pragma unroll
            for (int r = 0; r < 4; ++r) {
                float v0 = 2.f * acc[qs][0][r] - sqr[qs][r] - sj0;
                float v1 = 2.f * acc[qs][1][r] - sqr[qs][r] - sj1;
                int q = qs * 16 + 4 * kgrp + r;
                if (v0 >= taum[qs][r]) {
                    int p = atomicAdd(&qcnt[q], 1);
                    if (p < 64) qix[p * 33 + q] = step * 128 + jl0;
                }
                if (v1 >= taum[qs][r]) {
                    int p = atomicAdd(&qcnt[q], 1);
                    if (p < 64) qix[p * 33 + q] = step * 128 + jl1;
                }
            }
    }

    // ---------------- exact fp32 recompute of queued candidates ----------------
    __syncthreads();
    {
        int q = t >> 3;                       // 8 threads per query
        int cnt = qcnt[q]; if (cnt > 64) cnt = 64;
        float sqqe = sqg[q0 + q];
        const f4* qrow = (const f4*)&xqe[q * 68];
        for (int p = t & 7; p < cnt; p += 8) {
            int j = qix[p * 33 + q];
            const f4* jrow = (const f4*)&xt[((size_t)(b * 4096 + j)) * 64];
            float s = 0.f;
#pragma unroll
            for (int cc = 0; cc < 16; ++cc) {
                f4 a = qrow[cc];
                f4 bv = jrow[cc];
                s = fmaf(a[0], bv[0], s);
                s = fmaf(a[1], bv[1], s);
                s = fmaf(a[2], bv[2], s);
                s = fmaf(a[3], bv[3], s);
            }
            qval[p * 33 + q] = 2.f * s - sqqe - sqg[j];
        }
    }
    __syncthreads();

    if (t < 32) {
        int cnt = qcnt[t]; if (cnt > 64) cnt = 64;
        float tv[20]; int ti[20];
#pragma unroll
        for (int p = 0; p < 20; ++p) { tv[p] = -INFINITY; ti[p] = 0x7fffffff; }
#pragma unroll 1
        for (int p = 0; p < cnt; ++p)
            topk_insert(tv, ti, qval[p * 33 + t], qix[p * 33 + t]);
#pragma unroll
        for (int p = 0; p < 20; ++p)
            idxo[((size_t)(b * 4096 + q0 + t)) * 20 + p] = ti[p];
    }
}

// ---------------- ugemm: u1 = X^T W1^T, u2 = X^T (W2-W1)^T ----------------
__global__ void ugemm_kernel(const float* __restrict__ pts, const float* __restrict__ W,
                             float* __restrict__ u1, float* __restrict__ u2) {
    __shared__ float W1l[64 * 65];
    __shared__ float W2l[64 * 65];
    int t  = threadIdx.x;
    int b  = blockIdx.x >> 6;
    int j0 = (blockIdx.x & 63) << 6;
    int o  = t & 63, jg = t >> 6;

#pragma unroll
    for (int s = 0; s < 16; ++s) {
        int lin = s * 256 + t;
        int oo = lin >> 6, c = lin & 63;
        float w1 = W[oo * 128 + c];
        W1l[oo * 65 + c] = w1;
        W2l[oo * 65 + c] = W[oo * 128 + 64 + c] - w1;
    }
    __syncthreads();

    float acc1[16], acc2[16];
#pragma unroll
    for (int jj = 0; jj < 16; ++jj) { acc1[jj] = 0.f; acc2[jj] = 0.f; }

    const float* pbj = pts + (size_t)b * 64 * 4096 + j0 + jg * 16;
#pragma unroll 4
    for (int c = 0; c < 64; ++c) {
        float w1 = W1l[o * 65 + c];
        float w2 = W2l[o * 65 + c];
#pragma unroll
        for (int jj = 0; jj < 16; ++jj) {
            float p = pbj[(size_t)c * 4096 + jj];
            acc1[jj] = fmaf(w1, p, acc1[jj]);
            acc2[jj] = fmaf(w2, p, acc2[jj]);
        }
    }
#pragma unroll
    for (int jj = 0; jj < 16; ++jj) {
        int j = j0 + jg * 16 + jj;
        u1[(size_t)(b * 4096 + j) * 64 + o] = acc1[jj];
        u2[(size_t)(b * 4096 + j) * 64 + o] = acc2[jj];
    }
}

// ---------------- gather: y = u1[idx] + u2 ; max_k + global stats ----------------
__global__ void gather_kernel(const float* __restrict__ u1, const float* __restrict__ u2,
                              const int* __restrict__ idxi, float* __restrict__ ymax,
                              float* __restrict__ stats) {
    __shared__ float red[2 * 4 * 64];
    int t  = threadIdx.x;
    int o  = t & 63, ng = t >> 6;
    int b  = blockIdx.x >> 10;
    int n  = ((blockIdx.x & 1023) << 2) + ng;
    int bn = b * 4096 + n;

    float v2 = u2[(size_t)bn * 64 + o];
    float m = -INFINITY, s = 0.f, q = 0.f;
#pragma unroll
    for (int k = 0; k < 20; ++k) {
        int j = idxi[(size_t)bn * 20 + k];
        float y = u1[(size_t)(b * 4096 + j) * 64 + o] + v2;
        m = fmaxf(m, y);
        s += y;
        q = fmaf(y, y, q);
    }
    ymax[(size_t)bn * 64 + o] = m;
    red[ng * 64 + o] = s;
    red[256 + ng * 64 + o] = q;
    __syncthreads();
    if (t < 64) {
        float s_ = red[t] + red[64 + t] + red[128 + t] + red[192 + t];
        float q_ = red[256 + t] + red[256 + 64 + t] + red[256 + 128 + t] + red[256 + 192 + t];
        atomicAdd(&stats[b * 64 + t], s_);
        atomicAdd(&stats[256 + b * 64 + t], q_);
    }
}

// ---------------- finalize ----------------
__global__ void finalize_kernel(const float* __restrict__ ymax, const float* __restrict__ stats,
                                float* __restrict__ out) {
    int gid = blockIdx.x * 256 + threadIdx.x;   // 1,048,576
    int n = gid & 4095;
    int o = (gid >> 12) & 63;
    int b = gid >> 18;
    const float cnt = (float)(N_ * K_);
    float mean = stats[b * 64 + o] / cnt;
    float var  = stats[256 + b * 64 + o] / cnt - mean * mean;
    float inv  = rsqrtf(var + EPS_);
    float v = ymax[(size_t)(b * 4096 + n) * 64 + o];
    float z = (v - mean) * inv;
    out[gid] = z >= 0.f ? z : NSL_ * z;
}

extern "C" void kernel_launch(void* const* d_in, const int* in_sizes, int n_in,
                              void* d_out, int out_size, void* d_ws, size_t ws_size,
                              hipStream_t stream) {
    const float* pts = (const float*)d_in[0];
    const float* W   = (const float*)d_in[1];
    float* out = (float*)d_out;
    char* ws = (char*)d_ws;

    // region A (0..4MB): Xh(2MB)+Xl(2MB) during knn; u1 afterwards
    // region B (4..8MB): xt during knn; u2 afterwards
    h4*    Xh    = (h4*)(ws);
    h4*    Xl    = (h4*)(ws + 2097152);
    float* u1    = (float*)(ws);
    float* xt    = (float*)(ws + 4194304);
    float* u2    = (float*)(ws + 4194304);
    float* ymax  = (float*)(ws + 8388608);
    float* sq    = (float*)(ws + 12582912);
    int*   idx   = (int*)  (ws + 12648448);
    float* stats = (float*)(ws + 13959168);

    hipMemsetAsync(stats, 0, 512 * sizeof(float), stream);
    split_kernel    <<<1024, 256, 0, stream>>>(pts, Xh, Xl);
    sq_kernel       <<<64,   256, 0, stream>>>(pts, sq);
    transpose_kernel<<<256,  256, 0, stream>>>(pts, xt);
    knn3_kernel     <<<512,  256, 0, stream>>>(Xh, Xl, xt, sq, idx);
    ugemm_kernel    <<<256,  256, 0, stream>>>(pts, W, u1, u2);
    gather_kernel   <<<4096, 256, 0, stream>>>(u1, u2, idx, ymax, stats);
    finalize_kernel <<<4096, 256, 0, stream>>>(ymax, stats, out);
}

// Round 8
// 296.454 us; speedup vs baseline: 3.9467x; 1.1693x over previous
//
#include <hip/hip_runtime.h>
#include <math.h>

#define B_    4
#define N_    4096
#define K_    20
#define EPS_  1e-5f
#define NSL_  0.2f
#define MARGIN_ 0.05f
#define QCAP  64

typedef _Float16 h8 __attribute__((ext_vector_type(8)));
typedef float    f4 __attribute__((ext_vector_type(4)));

#define GLD16(gp, lp) __builtin_amdgcn_global_load_lds( \
    (const __attribute__((address_space(1))) void*)(gp), \
    (__attribute__((address_space(3))) void*)(lp), 16, 0, 0)
#define GLD4(gp, lp) __builtin_amdgcn_global_load_lds( \
    (const __attribute__((address_space(1))) void*)(gp), \
    (__attribute__((address_space(3))) void*)(lp), 4, 0, 0)

// ---------------- prep: f16 split (8-ch groups) + sq, one pass over pts ----------------
__global__ void prep_kernel(const float* __restrict__ pts,
                            h8* __restrict__ Xh, h8* __restrict__ Xl,
                            float* __restrict__ sq) {
    int gid = blockIdx.x * 256 + threadIdx.x;   // 16384 = B*N
    int b = gid >> 12, n = gid & 4095;
    const float* p = pts + (size_t)b * 64 * 4096 + n;
    float s = 0.f;
#pragma unroll
    for (int g = 0; g < 8; ++g) {
        h8 hh, ll;
#pragma unroll
        for (int i = 0; i < 8; ++i) {
            float x = p[(size_t)(g * 8 + i) * 4096];
            s = fmaf(x, x, s);
            _Float16 h = (_Float16)x;
            hh[i] = h;
            ll[i] = (_Float16)(x - (float)h);
        }
        Xh[(size_t)(b * 8 + g) * 4096 + n] = hh;
        Xl[(size_t)(b * 8 + g) * 4096 + n] = ll;
    }
    sq[gid] = s;
}

// ---------------- top-20 insertion (sorted desc by (val, -idx)) ----------------
__device__ __forceinline__ void topk_insert(float (&tv)[20], int (&ti)[20], float v, int ix) {
    if (v > tv[19] || (v == tv[19] && ix < ti[19])) {
        tv[19] = v; ti[19] = ix;
#pragma unroll
        for (int p = 19; p > 0; --p) {
            bool sw = (tv[p] > tv[p - 1]) || (tv[p] == tv[p - 1] && ti[p] < ti[p - 1]);
            float av = tv[p - 1]; int ai = ti[p - 1];
            float bv = tv[p];     int bi = ti[p];
            tv[p - 1] = sw ? bv : av;  ti[p - 1] = sw ? bi : ai;
            tv[p]     = sw ? av : bv;  ti[p]     = sw ? ai : bi;
        }
    }
}

// ---------------- knn4: 16x16x32 MFMA, dbuf async staging, 2-pass + exact re-rank ----------------
// v-scale: v = 2<q,j> - sq_j  (sq_q constant per query: ranking-invariant, dropped)
// LDS (bytes):
//   jHs [2][8][64] h8      0 .. 16384
//   jLs [2][8][64] h8  16384 .. 32768
//   qHs [8][32]    h8  32768 .. 36864
//   qLs [8][32]    h8  36864 .. 40960
//   xqe [32][68]  f32  40960 .. 49664
//   sqjl[2][64]   f32  49664 .. 50176
//   tauv[32]      f32  50176 .. 50304
//   qcnt[32]      int  50304 .. 50432
//   qix [64][33]  int  50432 .. 58880
//   coll[128][33] f32  overlay @0 (between passes)
//   qval[64][33]  f32  overlay @0 (after pass B)
__global__ __launch_bounds__(256) void knn4_kernel(
        const h8* __restrict__ Xh, const h8* __restrict__ Xl,
        const float* __restrict__ sqa, int* __restrict__ idxo) {
    __shared__ __align__(16) char smem[58880];
    h8*    jHs  = (h8*)(smem);
    h8*    jLs  = (h8*)(smem + 16384);
    h8*    qHs  = (h8*)(smem + 32768);
    h8*    qLs  = (h8*)(smem + 36864);
    float* xqe  = (float*)(smem + 40960);
    float* sqjl = (float*)(smem + 49664);
    float* tauv = (float*)(smem + 50176);
    int*   qcnt = (int*)  (smem + 50304);
    int*   qix  = (int*)  (smem + 50432);
    float* coll = (float*)(smem);
    float* qval = (float*)(smem);

    int t    = threadIdx.x;
    int lane = t & 63, w = t >> 6;
    int c15  = lane & 15, g4 = lane >> 4;
    int b    = blockIdx.x >> 7;
    int q0   = (blockIdx.x & 127) << 5;
    const h8* XhB = Xh + (size_t)b * 8 * 4096;
    const h8* XlB = Xl + (size_t)b * 8 * 4096;
    const float* sqg = sqa + b * 4096;

    // stage query fragments (one h8 per thread)
    {
        int g = t >> 5, q = t & 31;
        qHs[g * 32 + q] = XhB[(size_t)g * 4096 + q0 + q];
        qLs[g * 32 + q] = XlB[(size_t)g * 4096 + q0 + q];
    }
    __syncthreads();
    // reconstructed fp32 query rows for exact re-rank
#pragma unroll
    for (int s = 0; s < 8; ++s) {
        int idx = s * 256 + t;          // 2048 = 32q * 64c
        int q = idx >> 6, c = idx & 63;
        xqe[q * 68 + c] = (float)qHs[(c >> 3) * 32 + q][c & 7]
                        + (float)qLs[(c >> 3) * 32 + q][c & 7];
    }

    // async stage of one 64-j tile into buffer nb (wave w stages groups w and w+4)
    auto stage = [&](int nb, int jb) {
        GLD16(XhB + (size_t)w       * 4096 + jb + lane, jHs + nb * 512 + w       * 64);
        GLD16(XhB + (size_t)(w + 4) * 4096 + jb + lane, jHs + nb * 512 + (w + 4) * 64);
        GLD16(XlB + (size_t)w       * 4096 + jb + lane, jLs + nb * 512 + w       * 64);
        GLD16(XlB + (size_t)(w + 4) * 4096 + jb + lane, jLs + nb * 512 + (w + 4) * 64);
        if (w == 0) GLD4(sqg + jb + lane, sqjl + nb * 64);
    };

    f4 a0, a1;
    auto sweep = [&](int cur) {
        a0 = (f4){0.f, 0.f, 0.f, 0.f};
        a1 = (f4){0.f, 0.f, 0.f, 0.f};
#pragma unroll
        for (int kc = 0; kc < 2; ++kc) {
            int g = kc * 4 + g4;
            h8 bh  = jHs[cur * 512 + g * 64 + w * 16 + c15];
            h8 bl  = jLs[cur * 512 + g * 64 + w * 16 + c15];
            h8 qh0 = qHs[g * 32 + c15];
            h8 ql0 = qLs[g * 32 + c15];
            h8 qh1 = qHs[g * 32 + 16 + c15];
            h8 ql1 = qLs[g * 32 + 16 + c15];
            a0 = __builtin_amdgcn_mfma_f32_16x16x32_f16(qh0, bh, a0, 0, 0, 0);
            a0 = __builtin_amdgcn_mfma_f32_16x16x32_f16(qh0, bl, a0, 0, 0, 0);
            a0 = __builtin_amdgcn_mfma_f32_16x16x32_f16(ql0, bh, a0, 0, 0, 0);
            a1 = __builtin_amdgcn_mfma_f32_16x16x32_f16(qh1, bh, a1, 0, 0, 0);
            a1 = __builtin_amdgcn_mfma_f32_16x16x32_f16(qh1, bl, a1, 0, 0, 0);
            a1 = __builtin_amdgcn_mfma_f32_16x16x32_f16(ql1, bh, a1, 0, 0, 0);
        }
    };

    // ---------------- PASS A: per-lane top-2 in v-scale ----------------
    float t0v[2][4], t1v[2][4];
#pragma unroll
    for (int qs = 0; qs < 2; ++qs)
#pragma unroll
        for (int r = 0; r < 4; ++r) { t0v[qs][r] = -INFINITY; t1v[qs][r] = -INFINITY; }

    stage(0, 0);
    __syncthreads();
    for (int step = 0; step < 64; ++step) {
        int cur = step & 1;
        if (step < 63) stage(cur ^ 1, (step + 1) * 64);
        sweep(cur);
        float sj = sqjl[cur * 64 + w * 16 + c15];
#pragma unroll
        for (int r = 0; r < 4; ++r) {
            float v0 = 2.f * a0[r] - sj;
            t1v[0][r] = fminf(t0v[0][r], fmaxf(t1v[0][r], v0));
            t0v[0][r] = fmaxf(t0v[0][r], v0);
            float v1 = 2.f * a1[r] - sj;
            t1v[1][r] = fminf(t0v[1][r], fmaxf(t1v[1][r], v1));
            t0v[1][r] = fmaxf(t0v[1][r], v1);
        }
        __syncthreads();
    }

    // dump top-2 (stride-33), merge -> tau per query
    int s0 = w * 32 + c15 * 2;
#pragma unroll
    for (int qs = 0; qs < 2; ++qs)
#pragma unroll
        for (int r = 0; r < 4; ++r) {
            int q = qs * 16 + g4 * 4 + r;
            coll[(s0 + 0) * 33 + q] = t0v[qs][r];
            coll[(s0 + 1) * 33 + q] = t1v[qs][r];
        }
    __syncthreads();
    if (t < 32) {
        float tv[20];
#pragma unroll
        for (int p = 0; p < 20; ++p) tv[p] = -INFINITY;
#pragma unroll 1
        for (int s = 0; s < 128; ++s) {
            float v = coll[s * 33 + t];
            if (v > tv[19]) {
                tv[19] = v;
#pragma unroll
                for (int p = 19; p > 0; --p) {
                    float a = tv[p - 1], bb = tv[p];
                    tv[p - 1] = fmaxf(a, bb);
                    tv[p]     = fminf(a, bb);
                }
            }
        }
        tauv[t] = tv[19] - MARGIN_;
        qcnt[t] = 0;
    }
    __syncthreads();

    float taur[2][4];
#pragma unroll
    for (int qs = 0; qs < 2; ++qs)
#pragma unroll
        for (int r = 0; r < 4; ++r)
            taur[qs][r] = tauv[qs * 16 + g4 * 4 + r];

    // ---------------- PASS B: filter into per-query queues ----------------
    stage(0, 0);
    __syncthreads();
    for (int step = 0; step < 64; ++step) {
        int cur = step & 1;
        if (step < 63) stage(cur ^ 1, (step + 1) * 64);
        sweep(cur);
        float sj = sqjl[cur * 64 + w * 16 + c15];
        int jg = step * 64 + w * 16 + c15;
#pragma unroll
        for (int r = 0; r < 4; ++r) {
            float v0 = 2.f * a0[r] - sj;
            if (v0 >= taur[0][r]) {
                int q = g4 * 4 + r;
                int p = atomicAdd(&qcnt[q], 1);
                if (p < QCAP) qix[p * 33 + q] = jg;
            }
            float v1 = 2.f * a1[r] - sj;
            if (v1 >= taur[1][r]) {
                int q = 16 + g4 * 4 + r;
                int p = atomicAdd(&qcnt[q], 1);
                if (p < QCAP) qix[p * 33 + q] = jg;
            }
        }
        __syncthreads();
    }

    // ---------------- exact fp32 re-rank of queued candidates ----------------
    {
        int q = t >> 3;                       // 8 threads per query
        int cnt = qcnt[q]; if (cnt > QCAP) cnt = QCAP;
        for (int p = t & 7; p < cnt; p += 8) {
            int j = qix[p * 33 + q];
            float s = 0.f;
#pragma unroll
            for (int g = 0; g < 8; ++g) {
                h8 jh = XhB[(size_t)g * 4096 + j];
                h8 jl = XlB[(size_t)g * 4096 + j];
#pragma unroll
                for (int i = 0; i < 8; ++i) {
                    float xj = (float)jh[i] + (float)jl[i];
                    s = fmaf(xqe[q * 68 + g * 8 + i], xj, s);
                }
            }
            qval[p * 33 + q] = 2.f * s - sqg[j];
        }
    }
    __syncthreads();

    if (t < 32) {
        int cnt = qcnt[t]; if (cnt > QCAP) cnt = QCAP;
        float tv[20]; int ti[20];
#pragma unroll
        for (int p = 0; p < 20; ++p) { tv[p] = -INFINITY; ti[p] = 0x7fffffff; }
#pragma unroll 1
        for (int p = 0; p < cnt; ++p)
            topk_insert(tv, ti, qval[p * 33 + t], qix[p * 33 + t]);
#pragma unroll
        for (int p = 0; p < 20; ++p)
            idxo[((size_t)(b * 4096 + q0 + t)) * 20 + p] = ti[p];
    }
}

// ---------------- ugemm: u1 = X^T W1^T, u2 = X^T (W2-W1)^T ----------------
__global__ void ugemm_kernel(const float* __restrict__ pts, const float* __restrict__ W,
                             float* __restrict__ u1, float* __restrict__ u2) {
    __shared__ float W1l[64 * 65];
    __shared__ float W2l[64 * 65];
    int t  = threadIdx.x;
    int b  = blockIdx.x >> 6;
    int j0 = (blockIdx.x & 63) << 6;
    int o  = t & 63, jg = t >> 6;

#pragma unroll
    for (int s = 0; s < 16; ++s) {
        int lin = s * 256 + t;
        int oo = lin >> 6, c = lin & 63;
        float w1 = W[oo * 128 + c];
        W1l[oo * 65 + c] = w1;
        W2l[oo * 65 + c] = W[oo * 128 + 64 + c] - w1;
    }
    __syncthreads();

    float acc1[16], acc2[16];
#pragma unroll
    for (int jj = 0; jj < 16; ++jj) { acc1[jj] = 0.f; acc2[jj] = 0.f; }

    const float* pbj = pts + (size_t)b * 64 * 4096 + j0 + jg * 16;
#pragma unroll 4
    for (int c = 0; c < 64; ++c) {
        float w1 = W1l[o * 65 + c];
        float w2 = W2l[o * 65 + c];
#pragma unroll
        for (int jj = 0; jj < 16; ++jj) {
            float p = pbj[(size_t)c * 4096 + jj];
            acc1[jj] = fmaf(w1, p, acc1[jj]);
            acc2[jj] = fmaf(w2, p, acc2[jj]);
        }
    }
#pragma unroll
    for (int jj = 0; jj < 16; ++jj) {
        int j = j0 + jg * 16 + jj;
        u1[(size_t)(b * 4096 + j) * 64 + o] = acc1[jj];
        u2[(size_t)(b * 4096 + j) * 64 + o] = acc2[jj];
    }
}

// ---------------- gather: y = u1[idx] + u2 ; max_k + global stats ----------------
__global__ void gather_kernel(const float* __restrict__ u1, const float* __restrict__ u2,
                              const int* __restrict__ idxi, float* __restrict__ ymax,
                              float* __restrict__ stats) {
    __shared__ float red[2 * 4 * 64];
    int t  = threadIdx.x;
    int o  = t & 63, ng = t >> 6;
    int b  = blockIdx.x >> 10;
    int n  = ((blockIdx.x & 1023) << 2) + ng;
    int bn = b * 4096 + n;

    float v2 = u2[(size_t)bn * 64 + o];
    float m = -INFINITY, s = 0.f, q = 0.f;
#pragma unroll
    for (int k = 0; k < 20; ++k) {
        int j = idxi[(size_t)bn * 20 + k];
        float y = u1[(size_t)(b * 4096 + j) * 64 + o] + v2;
        m = fmaxf(m, y);
        s += y;
        q = fmaf(y, y, q);
    }
    ymax[(size_t)bn * 64 + o] = m;
    red[ng * 64 + o] = s;
    red[256 + ng * 64 + o] = q;
    __syncthreads();
    if (t < 64) {
        float s_ = red[t] + red[64 + t] + red[128 + t] + red[192 + t];
        float q_ = red[256 + t] + red[256 + 64 + t] + red[256 + 128 + t] + red[256 + 192 + t];
        atomicAdd(&stats[b * 64 + t], s_);
        atomicAdd(&stats[256 + b * 64 + t], q_);
    }
}

// ---------------- finalize ----------------
__global__ void finalize_kernel(const float* __restrict__ ymax, const float* __restrict__ stats,
                                float* __restrict__ out) {
    int gid = blockIdx.x * 256 + threadIdx.x;   // 1,048,576
    int n = gid & 4095;
    int o = (gid >> 12) & 63;
    int b = gid >> 18;
    const float cnt = (float)(N_ * K_);
    float mean = stats[b * 64 + o] / cnt;
    float var  = stats[256 + b * 64 + o] / cnt - mean * mean;
    float inv  = rsqrtf(var + EPS_);
    float v = ymax[(size_t)(b * 4096 + n) * 64 + o];
    float z = (v - mean) * inv;
    out[gid] = z >= 0.f ? z : NSL_ * z;
}

extern "C" void kernel_launch(void* const* d_in, const int* in_sizes, int n_in,
                              void* d_out, int out_size, void* d_ws, size_t ws_size,
                              hipStream_t stream) {
    const float* pts = (const float*)d_in[0];
    const float* W   = (const float*)d_in[1];
    float* out = (float*)d_out;
    char* ws = (char*)d_ws;

    // Xh8/Xl8 live in [0,4MB) during knn; ymax overlays them afterwards.
    h8*    Xh    = (h8*)(ws);                     // 2 MB
    h8*    Xl    = (h8*)(ws + 2097152);           // 2 MB
    float* ymax  = (float*)(ws);                  // 4 MB (after knn4)
    float* u1    = (float*)(ws + 4194304);        // 4 MB
    float* u2    = (float*)(ws + 8388608);        // 4 MB
    float* sq    = (float*)(ws + 12582912);       // 64 KB
    int*   idx   = (int*)  (ws + 12648448);       // 1.25 MB
    float* stats = (float*)(ws + 13959168);       // 2 KB

    hipMemsetAsync(stats, 0, 512 * sizeof(float), stream);
    prep_kernel     <<<64,   256, 0, stream>>>(pts, Xh, Xl, sq);
    knn4_kernel     <<<512,  256, 0, stream>>>(Xh, Xl, sq, idx);
    ugemm_kernel    <<<256,  256, 0, stream>>>(pts, W, u1, u2);
    gather_kernel   <<<4096, 256, 0, stream>>>(u1, u2, idx, ymax, stats);
    finalize_kernel <<<4096, 256, 0, stream>>>(ymax, stats, out);
}

// Round 10
// 270.881 us; speedup vs baseline: 4.3193x; 1.0944x over previous
//
#include <hip/hip_runtime.h>
#include <math.h>

#define B_    4
#define N_    4096
#define K_    20
#define EPS_  1e-5f
#define NSL_  0.2f
#define MARGIN_ 0.05f
#define QCAP  64

typedef _Float16 h8 __attribute__((ext_vector_type(8)));
typedef float    f4 __attribute__((ext_vector_type(4)));

#define MFMA32(A, Bv, C) __builtin_amdgcn_mfma_f32_16x16x32_f16((A), (Bv), (C), 0, 0, 0)

// ---------------- prep: f16 split (8-ch groups) + sq, one pass over pts ----------------
__global__ void prep_kernel(const float* __restrict__ pts,
                            h8* __restrict__ Xh, h8* __restrict__ Xl,
                            float* __restrict__ sq) {
    int gid = blockIdx.x * 256 + threadIdx.x;   // 16384 = B*N
    int b = gid >> 12, n = gid & 4095;
    const float* p = pts + (size_t)b * 64 * 4096 + n;
    float s = 0.f;
#pragma unroll
    for (int g = 0; g < 8; ++g) {
        h8 hh, ll;
#pragma unroll
        for (int i = 0; i < 8; ++i) {
            float x = p[(size_t)(g * 8 + i) * 4096];
            s = fmaf(x, x, s);
            _Float16 h = (_Float16)x;
            hh[i] = h;
            ll[i] = (_Float16)(x - (float)h);
        }
        Xh[(size_t)(b * 8 + g) * 4096 + n] = hh;
        Xl[(size_t)(b * 8 + g) * 4096 + n] = ll;
    }
    sq[gid] = s;
}

// ---------------- top-20 insertion (sorted desc by (val, -idx)) ----------------
__device__ __forceinline__ void topk_insert(float (&tv)[20], int (&ti)[20], float v, int ix) {
    if (v > tv[19] || (v == tv[19] && ix < ti[19])) {
        tv[19] = v; ti[19] = ix;
#pragma unroll
        for (int p = 19; p > 0; --p) {
            bool sw = (tv[p] > tv[p - 1]) || (tv[p] == tv[p - 1] && ti[p] < ti[p - 1]);
            float av = tv[p - 1]; int ai = ti[p - 1];
            float bv = tv[p];     int bi = ti[p];
            tv[p - 1] = sw ? bv : av;  ti[p - 1] = sw ? bi : ai;
            tv[p]     = sw ? av : bv;  ti[p]     = sw ? ai : bi;
        }
    }
}

// ---------------- knn5: register-streamed B, no in-loop barriers ----------------
// Each wave: Q-fragments (8 h8) hoisted to regs; per step loads its own 4 B-frags
// + sq directly global->reg (L2-resident, no cross-wave reuse -> no LDS staging).
// v-scale: v = 2<q,j> - sq_j (sq_q constant per query, ranking-invariant).
// LDS (bytes):
//   coll[128][33] f32 @0     (16896)   pass-A top-2 collection
//   xqe [32][68]  f32 @0     (8704)    overlay after tau-merge
//   qval[64][33]  f32 @8704  (8448)
//   qix [64][33]  int @17152 (8448)
//   tauv[32]      f32 @25600
//   qcnt[32]      int @25728  -> total 25856
__global__ __launch_bounds__(256, 4) void knn5_kernel(
        const h8* __restrict__ Xh, const h8* __restrict__ Xl,
        const float* __restrict__ sqa, int* __restrict__ idxo) {
    __shared__ __align__(16) char smem[25856];
    float* coll = (float*)(smem);
    float* xqe  = (float*)(smem);
    float* qval = (float*)(smem + 8704);
    int*   qix  = (int*)  (smem + 17152);
    float* tauv = (float*)(smem + 25600);
    int*   qcnt = (int*)  (smem + 25728);

    int t    = threadIdx.x;
    int lane = t & 63, w = t >> 6;
    int c15  = lane & 15, g4 = lane >> 4;
    int b    = blockIdx.x >> 7;
    int q0   = (blockIdx.x & 127) << 5;
    const h8* XhB = Xh + (size_t)b * 8 * 4096;
    const h8* XlB = Xl + (size_t)b * 8 * 4096;
    const float* sqg = sqa + b * 4096;

    // Q fragments -> registers (loop-invariant)
    const h8* QHlo = XhB + (size_t)g4 * 4096 + q0;
    const h8* QHhi = XhB + (size_t)(g4 + 4) * 4096 + q0;
    const h8* QLlo = XlB + (size_t)g4 * 4096 + q0;
    const h8* QLhi = XlB + (size_t)(g4 + 4) * 4096 + q0;
    h8 qh0_lo = QHlo[c15], qh1_lo = QHlo[16 + c15];
    h8 qh0_hi = QHhi[c15], qh1_hi = QHhi[16 + c15];
    h8 ql0_lo = QLlo[c15], ql1_lo = QLlo[16 + c15];
    h8 ql0_hi = QLhi[c15], ql1_hi = QLhi[16 + c15];

    // B stream base pointers (this lane's j-stripe: j = step*64 + w*16 + c15)
    int jb0 = w * 16 + c15;
    const h8* pbh_lo = XhB + (size_t)g4 * 4096 + jb0;
    const h8* pbh_hi = XhB + (size_t)(g4 + 4) * 4096 + jb0;
    const h8* pbl_lo = XlB + (size_t)g4 * 4096 + jb0;
    const h8* pbl_hi = XlB + (size_t)(g4 + 4) * 4096 + jb0;
    const float* psj = sqg + jb0;

    // ---------------- PASS A: per-lane top-2 in v-scale ----------------
    float t0v[2][4], t1v[2][4];
#pragma unroll
    for (int qs = 0; qs < 2; ++qs)
#pragma unroll
        for (int r = 0; r < 4; ++r) { t0v[qs][r] = -INFINITY; t1v[qs][r] = -INFINITY; }

    {
        h8 bh_lo = pbh_lo[0], bh_hi = pbh_hi[0];
        h8 bl_lo = pbl_lo[0], bl_hi = pbl_hi[0];
        float sj = psj[0];
        for (int step = 0; step < 64; ++step) {
            int noff = ((step < 63) ? (step + 1) : 63) * 64;
            h8 nbh_lo = pbh_lo[noff], nbh_hi = pbh_hi[noff];
            h8 nbl_lo = pbl_lo[noff], nbl_hi = pbl_hi[noff];
            float nsj = psj[noff];

            f4 a0 = (f4){0.f, 0.f, 0.f, 0.f};
            f4 a1 = (f4){0.f, 0.f, 0.f, 0.f};
            a0 = MFMA32(qh0_lo, bh_lo, a0);
            a0 = MFMA32(qh0_lo, bl_lo, a0);
            a0 = MFMA32(ql0_lo, bh_lo, a0);
            a0 = MFMA32(qh0_hi, bh_hi, a0);
            a0 = MFMA32(qh0_hi, bl_hi, a0);
            a0 = MFMA32(ql0_hi, bh_hi, a0);
            a1 = MFMA32(qh1_lo, bh_lo, a1);
            a1 = MFMA32(qh1_lo, bl_lo, a1);
            a1 = MFMA32(ql1_lo, bh_lo, a1);
            a1 = MFMA32(qh1_hi, bh_hi, a1);
            a1 = MFMA32(qh1_hi, bl_hi, a1);
            a1 = MFMA32(ql1_hi, bh_hi, a1);

#pragma unroll
            for (int r = 0; r < 4; ++r) {
                float v0 = 2.f * a0[r] - sj;
                t1v[0][r] = fminf(t0v[0][r], fmaxf(t1v[0][r], v0));
                t0v[0][r] = fmaxf(t0v[0][r], v0);
                float v1 = 2.f * a1[r] - sj;
                t1v[1][r] = fminf(t0v[1][r], fmaxf(t1v[1][r], v1));
                t0v[1][r] = fmaxf(t0v[1][r], v1);
            }
            bh_lo = nbh_lo; bh_hi = nbh_hi;
            bl_lo = nbl_lo; bl_hi = nbl_hi;
            sj = nsj;
        }
    }

    // dump top-2 (stride-33) -> tau per query
    int s0 = w * 32 + c15 * 2;
#pragma unroll
    for (int qs = 0; qs < 2; ++qs)
#pragma unroll
        for (int r = 0; r < 4; ++r) {
            int q = qs * 16 + g4 * 4 + r;
            coll[(s0 + 0) * 33 + q] = t0v[qs][r];
            coll[(s0 + 1) * 33 + q] = t1v[qs][r];
        }
    __syncthreads();
    if (t < 32) {
        float tv[20];
#pragma unroll
        for (int p = 0; p < 20; ++p) tv[p] = -INFINITY;
#pragma unroll 1
        for (int s = 0; s < 128; ++s) {
            float v = coll[s * 33 + t];
            if (v > tv[19]) {
                tv[19] = v;
#pragma unroll
                for (int p = 19; p > 0; --p) {
                    float a = tv[p - 1], bb = tv[p];
                    tv[p - 1] = fmaxf(a, bb);
                    tv[p]     = fminf(a, bb);
                }
            }
        }
        tauv[t] = tv[19] - MARGIN_;
        qcnt[t] = 0;
    }
    __syncthreads();          // merge done; coll dead -> xqe may be written

    // fill exact fp32 query rows (overlay region): 256 threads = 32 q x 8 g
    {
        int q = t >> 3, g = t & 7;
        h8 hh = XhB[(size_t)g * 4096 + q0 + q];
        h8 ll = XlB[(size_t)g * 4096 + q0 + q];
#pragma unroll
        for (int i = 0; i < 8; ++i)
            xqe[q * 68 + g * 8 + i] = (float)hh[i] + (float)ll[i];
    }

    float taur[2][4];
#pragma unroll
    for (int qs = 0; qs < 2; ++qs)
#pragma unroll
        for (int r = 0; r < 4; ++r)
            taur[qs][r] = tauv[qs * 16 + g4 * 4 + r];

    // ---------------- PASS B: filter into per-query queues ----------------
    {
        h8 bh_lo = pbh_lo[0], bh_hi = pbh_hi[0];
        h8 bl_lo = pbl_lo[0], bl_hi = pbl_hi[0];
        float sj = psj[0];
        for (int step = 0; step < 64; ++step) {
            int noff = ((step < 63) ? (step + 1) : 63) * 64;
            h8 nbh_lo = pbh_lo[noff], nbh_hi = pbh_hi[noff];
            h8 nbl_lo = pbl_lo[noff], nbl_hi = pbl_hi[noff];
            float nsj = psj[noff];

            f4 a0 = (f4){0.f, 0.f, 0.f, 0.f};
            f4 a1 = (f4){0.f, 0.f, 0.f, 0.f};
            a0 = MFMA32(qh0_lo, bh_lo, a0);
            a0 = MFMA32(qh0_lo, bl_lo, a0);
            a0 = MFMA32(ql0_lo, bh_lo, a0);
            a0 = MFMA32(qh0_hi, bh_hi, a0);
            a0 = MFMA32(qh0_hi, bl_hi, a0);
            a0 = MFMA32(ql0_hi, bh_hi, a0);
            a1 = MFMA32(qh1_lo, bh_lo, a1);
            a1 = MFMA32(qh1_lo, bl_lo, a1);
            a1 = MFMA32(ql1_lo, bh_lo, a1);
            a1 = MFMA32(qh1_hi, bh_hi, a1);
            a1 = MFMA32(qh1_hi, bl_hi, a1);
            a1 = MFMA32(ql1_hi, bh_hi, a1);

            int jg = step * 64 + w * 16 + c15;
#pragma unroll
            for (int r = 0; r < 4; ++r) {
                float v0 = 2.f * a0[r] - sj;
                if (v0 >= taur[0][r]) {
                    int q = g4 * 4 + r;
                    int p = atomicAdd(&qcnt[q], 1);
                    if (p < QCAP) qix[p * 33 + q] = jg;
                }
                float v1 = 2.f * a1[r] - sj;
                if (v1 >= taur[1][r]) {
                    int q = 16 + g4 * 4 + r;
                    int p = atomicAdd(&qcnt[q], 1);
                    if (p < QCAP) qix[p * 33 + q] = jg;
                }
            }
            bh_lo = nbh_lo; bh_hi = nbh_hi;
            bl_lo = nbl_lo; bl_hi = nbl_hi;
            sj = nsj;
        }
    }
    __syncthreads();

    // ---------------- exact fp32 re-rank of queued candidates ----------------
    {
        int q = t >> 3;                       // 8 threads per query
        int cnt = qcnt[q]; if (cnt > QCAP) cnt = QCAP;
        for (int p = t & 7; p < cnt; p += 8) {
            int j = qix[p * 33 + q];
            float s = 0.f;
#pragma unroll
            for (int g = 0; g < 8; ++g) {
                h8 jh = XhB[(size_t)g * 4096 + j];
                h8 jl = XlB[(size_t)g * 4096 + j];
#pragma unroll
                for (int i = 0; i < 8; ++i) {
                    float xj = (float)jh[i] + (float)jl[i];
                    s = fmaf(xqe[q * 68 + g * 8 + i], xj, s);
                }
            }
            qval[p * 33 + q] = 2.f * s - sqg[j];
        }
    }
    __syncthreads();

    if (t < 32) {
        int cnt = qcnt[t]; if (cnt > QCAP) cnt = QCAP;
        float tv[20]; int ti[20];
#pragma unroll
        for (int p = 0; p < 20; ++p) { tv[p] = -INFINITY; ti[p] = 0x7fffffff; }
#pragma unroll 1
        for (int p = 0; p < cnt; ++p)
            topk_insert(tv, ti, qval[p * 33 + t], qix[p * 33 + t]);
#pragma unroll
        for (int p = 0; p < 20; ++p)
            idxo[((size_t)(b * 4096 + q0 + t)) * 20 + p] = ti[p];
    }
}

// ---------------- ugemm: u1 = X^T W1^T, u2 = X^T (W2-W1)^T ----------------
__global__ void ugemm_kernel(const float* __restrict__ pts, const float* __restrict__ W,
                             float* __restrict__ u1, float* __restrict__ u2) {
    __shared__ float W1l[64 * 65];
    __shared__ float W2l[64 * 65];
    int t  = threadIdx.x;
    int b  = blockIdx.x >> 6;
    int j0 = (blockIdx.x & 63) << 6;
    int o  = t & 63, jg = t >> 6;

#pragma unroll
    for (int s = 0; s < 16; ++s) {
        int lin = s * 256 + t;
        int oo = lin >> 6, c = lin & 63;
        float w1 = W[oo * 128 + c];
        W1l[oo * 65 + c] = w1;
        W2l[oo * 65 + c] = W[oo * 128 + 64 + c] - w1;
    }
    __syncthreads();

    float acc1[16], acc2[16];
#pragma unroll
    for (int jj = 0; jj < 16; ++jj) { acc1[jj] = 0.f; acc2[jj] = 0.f; }

    const float* pbj = pts + (size_t)b * 64 * 4096 + j0 + jg * 16;
#pragma unroll 4
    for (int c = 0; c < 64; ++c) {
        float w1 = W1l[o * 65 + c];
        float w2 = W2l[o * 65 + c];
#pragma unroll
        for (int jj = 0; jj < 16; ++jj) {
            float p = pbj[(size_t)c * 4096 + jj];
            acc1[jj] = fmaf(w1, p, acc1[jj]);
            acc2[jj] = fmaf(w2, p, acc2[jj]);
        }
    }
#pragma unroll
    for (int jj = 0; jj < 16; ++jj) {
        int j = j0 + jg * 16 + jj;
        u1[(size_t)(b * 4096 + j) * 64 + o] = acc1[jj];
        u2[(size_t)(b * 4096 + j) * 64 + o] = acc2[jj];
    }
}

// ---------------- gather: y = u1[idx] + u2 ; max_k + global stats ----------------
__global__ void gather_kernel(const float* __restrict__ u1, const float* __restrict__ u2,
                              const int* __restrict__ idxi, float* __restrict__ ymax,
                              float* __restrict__ stats) {
    __shared__ float red[2 * 4 * 64];
    int t  = threadIdx.x;
    int o  = t & 63, ng = t >> 6;
    int b  = blockIdx.x >> 10;
    int n  = ((blockIdx.x & 1023) << 2) + ng;
    int bn = b * 4096 + n;

    float v2 = u2[(size_t)bn * 64 + o];
    float m = -INFINITY, s = 0.f, q = 0.f;
#pragma unroll
    for (int k = 0; k < 20; ++k) {
        int j = idxi[(size_t)bn * 20 + k];
        float y = u1[(size_t)(b * 4096 + j) * 64 + o] + v2;
        m = fmaxf(m, y);
        s += y;
        q = fmaf(y, y, q);
    }
    ymax[(size_t)bn * 64 + o] = m;
    red[ng * 64 + o] = s;
    red[256 + ng * 64 + o] = q;
    __syncthreads();
    if (t < 64) {
        float s_ = red[t] + red[64 + t] + red[128 + t] + red[192 + t];
        float q_ = red[256 + t] + red[256 + 64 + t] + red[256 + 128 + t] + red[256 + 192 + t];
        atomicAdd(&stats[b * 64 + t], s_);
        atomicAdd(&stats[256 + b * 64 + t], q_);
    }
}

// ---------------- finalize ----------------
__global__ void finalize_kernel(const float* __restrict__ ymax, const float* __restrict__ stats,
                                float* __restrict__ out) {
    int gid = blockIdx.x * 256 + threadIdx.x;   // 1,048,576
    int n = gid & 4095;
    int o = (gid >> 12) & 63;
    int b = gid >> 18;
    const float cnt = (float)(N_ * K_);
    float mean = stats[b * 64 + o] / cnt;
    float var  = stats[256 + b * 64 + o] / cnt - mean * mean;
    float inv  = rsqrtf(var + EPS_);
    float v = ymax[(size_t)(b * 4096 + n) * 64 + o];
    float z = (v - mean) * inv;
    out[gid] = z >= 0.f ? z : NSL_ * z;
}

extern "C" void kernel_launch(void* const* d_in, const int* in_sizes, int n_in,
                              void* d_out, int out_size, void* d_ws, size_t ws_size,
                              hipStream_t stream) {
    const float* pts = (const float*)d_in[0];
    const float* W   = (const float*)d_in[1];
    float* out = (float*)d_out;
    char* ws = (char*)d_ws;

    // Xh8/Xl8 live in [0,4MB) during knn; ymax overlays them afterwards.
    h8*    Xh    = (h8*)(ws);                     // 2 MB
    h8*    Xl    = (h8*)(ws + 2097152);           // 2 MB
    float* ymax  = (float*)(ws);                  // 4 MB (after knn5)
    float* u1    = (float*)(ws + 4194304);        // 4 MB
    float* u2    = (float*)(ws + 8388608);        // 4 MB
    float* sq    = (float*)(ws + 12582912);       // 64 KB
    int*   idx   = (int*)  (ws + 12648448);       // 1.25 MB
    float* stats = (float*)(ws + 13959168);       // 2 KB

    hipMemsetAsync(stats, 0, 512 * sizeof(float), stream);
    prep_kernel     <<<64,   256, 0, stream>>>(pts, Xh, Xl, sq);
    knn5_kernel     <<<512,  256, 0, stream>>>(Xh, Xl, sq, idx);
    ugemm_kernel    <<<256,  256, 0, stream>>>(pts, W, u1, u2);
    gather_kernel   <<<4096, 256, 0, stream>>>(u1, u2, idx, ymax, stats);
    finalize_kernel <<<4096, 256, 0, stream>>>(ymax, stats, out);
}